// Round 1
// baseline (513.411 us; speedup 1.0000x reference)
//
#include <hip/hip_runtime.h>

#define T_DIM 64
#define N_DIM 2000
#define C_DIM 64
#define E_DIM 32000
#define ROWS (T_DIM * N_DIM)   // 128000
#define BN_EPS 1e-5f

// ---------------- prep kernels ----------------

__global__ void k_deg(const int* __restrict__ ei, int* __restrict__ deg) {
    int e = blockIdx.x * 256 + threadIdx.x;
    if (e < E_DIM) atomicAdd(&deg[ei[E_DIM + e]], 1);
}

__global__ void k_dinv(const int* __restrict__ deg, float* __restrict__ dinv) {
    int n = blockIdx.x * 256 + threadIdx.x;
    if (n < N_DIM) dinv[n] = rsqrtf((float)(deg[n] + 1));  // +1 self-loop
}

// exclusive prefix sum of deg[0..N_DIM) -> offs[0..N_DIM], single block of 1024
__global__ void k_scan(const int* __restrict__ deg, int* __restrict__ offs) {
    __shared__ int a[2048], b[2048];
    int tid = threadIdx.x;
    for (int i = tid; i < 2048; i += 1024) a[i] = (i < N_DIM) ? deg[i] : 0;
    __syncthreads();
    int* s = a; int* d = b;
    for (int off = 1; off < 2048; off <<= 1) {
        for (int i = tid; i < 2048; i += 1024)
            d[i] = s[i] + ((i >= off) ? s[i - off] : 0);
        __syncthreads();
        int* t = s; s = d; d = t;
    }
    for (int i = tid; i < 2048; i += 1024)
        if (i <= N_DIM) offs[i] = (i == 0) ? 0 : s[i - 1];
}

__global__ void k_fill(const int* __restrict__ ei, const int* __restrict__ offs,
                       const float* __restrict__ dinv, int* __restrict__ cursor,
                       int* __restrict__ ssrc, float* __restrict__ snorm) {
    int e = blockIdx.x * 256 + threadIdx.x;
    if (e < E_DIM) {
        int s = ei[e];
        int d = ei[E_DIM + e];
        int p = atomicAdd(&cursor[d], 1);
        int idx = offs[d] + p;
        ssrc[idx] = s;
        snorm[idx] = dinv[s] * dinv[d];
    }
}

// Wc1[k][i][o] = sum_j conv1_w[j,i,k] * gcn_w[j,o];  Wc2[k][i][o] = conv2_w[o,i,k]
// b1c[o] = sum_j conv1_b[j] * gcn_w[j,o]
__global__ void k_wprep(const float* __restrict__ c1w, const float* __restrict__ c1b,
                        const float* __restrict__ gw, const float* __restrict__ c2w,
                        float* __restrict__ Wc1, float* __restrict__ Wc2,
                        float* __restrict__ b1c) {
    int gid = blockIdx.x * 256 + threadIdx.x;   // 48 blocks * 256 = 12288
    if (gid < 3 * 64 * 64) {
        int k = gid >> 12;
        int rem = gid & 4095;
        int i = rem >> 6;
        int o = rem & 63;
        float s = 0.f;
        for (int j = 0; j < 64; ++j)
            s += c1w[j * 192 + i * 3 + k] * gw[j * 64 + o];
        Wc1[gid] = s;
        Wc2[gid] = c2w[o * 192 + i * 3 + k];
        if (gid < 64) {
            float bs = 0.f;
            for (int j = 0; j < 64; ++j) bs += c1b[j] * gw[j * 64 + gid];
            b1c[gid] = bs;
        }
    }
}

// ---------------- main GEMM: out[r][o] = bias[o] + sum_k sum_i A[r+(k-1)N][i]*W[k][i][o] ----------------
// block = 256 threads, tile 64 rows x 64 cols, 4x4 per thread.
__global__ __launch_bounds__(256, 2) void k_gemm(
    const float* __restrict__ A, const float* __restrict__ W,
    const float* __restrict__ bias, float* __restrict__ out,
    float* __restrict__ bnstats, int do_stats) {
    __shared__ __align__(16) float Wl[3 * 64 * 64];   // 48 KB
    __shared__ __align__(16) float At[64][68];        // [kk][r], padded, 17.4 KB
    __shared__ float ssum[64], ssq[64];

    int tid = threadIdx.x;
    int row0 = blockIdx.x * 64;

    for (int i = tid; i < 3 * 4096; i += 256) Wl[i] = W[i];
    if (do_stats && tid < 64) { ssum[tid] = 0.f; ssq[tid] = 0.f; }

    float acc[4][4] = {};
    int tx = tid & 15, ty = tid >> 4;
    int c0 = tx * 4, r0 = ty * 4;

    for (int k = 0; k < 3; ++k) {
        __syncthreads();
        for (int i = tid; i < 4096; i += 256) {
            int r = i >> 6, kk = i & 63;
            int gr = row0 + r;
            int t = gr / N_DIM;
            int ts = t + k - 1;
            float v = 0.f;
            if (ts >= 0 && ts < T_DIM) v = A[(gr + (k - 1) * N_DIM) * 64 + kk];
            At[kk][r] = v;
        }
        __syncthreads();
        const float* Wk = &Wl[k * 4096];
        #pragma unroll 8
        for (int kk = 0; kk < 64; ++kk) {
            float4 av = *(const float4*)&At[kk][r0];
            float4 wv = *(const float4*)&Wk[kk * 64 + c0];
            float a4[4] = {av.x, av.y, av.z, av.w};
            float w4[4] = {wv.x, wv.y, wv.z, wv.w};
            #pragma unroll
            for (int i = 0; i < 4; ++i)
                #pragma unroll
                for (int j = 0; j < 4; ++j)
                    acc[i][j] += a4[i] * w4[j];
        }
    }

    float b4[4] = {bias[c0], bias[c0 + 1], bias[c0 + 2], bias[c0 + 3]};
    float bsum[4] = {0.f, 0.f, 0.f, 0.f};
    float bsq[4] = {0.f, 0.f, 0.f, 0.f};
    #pragma unroll
    for (int i = 0; i < 4; ++i) {
        int gr = row0 + r0 + i;
        float4 v;
        v.x = acc[i][0] + b4[0];
        v.y = acc[i][1] + b4[1];
        v.z = acc[i][2] + b4[2];
        v.w = acc[i][3] + b4[3];
        *(float4*)&out[gr * 64 + c0] = v;
        if (do_stats) {
            bsum[0] += v.x; bsum[1] += v.y; bsum[2] += v.z; bsum[3] += v.w;
            bsq[0] += v.x * v.x; bsq[1] += v.y * v.y;
            bsq[2] += v.z * v.z; bsq[3] += v.w * v.w;
        }
    }
    if (do_stats) {
        #pragma unroll
        for (int j = 0; j < 4; ++j) {
            atomicAdd(&ssum[c0 + j], bsum[j]);
            atomicAdd(&ssq[c0 + j], bsq[j]);
        }
        __syncthreads();
        if (tid < 64) {
            atomicAdd(&bnstats[tid], ssum[tid]);
            atomicAdd(&bnstats[64 + tid], ssq[tid]);
        }
    }
}

// ---------------- GCN aggregation (CSR gather, no atomics) ----------------
__global__ __launch_bounds__(256) void k_gather(
    const float* __restrict__ xh, const int* __restrict__ offs,
    const int* __restrict__ ssrc, const float* __restrict__ snorm,
    const float* __restrict__ dinv, const float* __restrict__ gcn_b,
    float* __restrict__ h2) {
    int unit = blockIdx.x * 4 + (threadIdx.x >> 6);   // one wave per (t,n)
    int lane = threadIdx.x & 63;
    int t = unit / N_DIM;
    int n = unit - t * N_DIM;
    float dn = dinv[n];
    float acc = dn * dn * xh[unit * 64 + lane] + gcn_b[lane];
    int beg = offs[n], end = offs[n + 1];
    const float* base = xh + (size_t)t * N_DIM * 64;
    for (int j = beg; j < end; ++j) {
        acc += snorm[j] * base[ssrc[j] * 64 + lane];
    }
    h2[unit * 64 + lane] = acc;
}

// ---------------- BN (train-mode stats) + ReLU, in place ----------------
__global__ __launch_bounds__(256) void k_bn(float* __restrict__ io,
                                            const float* __restrict__ bnstats,
                                            const float* __restrict__ gamma,
                                            const float* __restrict__ beta) {
    __shared__ float sscale[64], sshift[64];
    int tid = threadIdx.x;
    if (tid < 64) {
        float m = bnstats[tid] * (1.0f / ROWS);
        float v = bnstats[64 + tid] * (1.0f / ROWS) - m * m;
        float sc = gamma[tid] * rsqrtf(v + BN_EPS);
        sscale[tid] = sc;
        sshift[tid] = beta[tid] - m * sc;
    }
    __syncthreads();
    const int total4 = ROWS * 64 / 4;
    for (int i4 = blockIdx.x * 256 + tid; i4 < total4; i4 += gridDim.x * 256) {
        float4 v = *(const float4*)(io + (size_t)i4 * 4);
        int c = (i4 * 4) & 63;
        v.x = fmaxf(v.x * sscale[c + 0] + sshift[c + 0], 0.f);
        v.y = fmaxf(v.y * sscale[c + 1] + sshift[c + 1], 0.f);
        v.z = fmaxf(v.z * sscale[c + 2] + sshift[c + 2], 0.f);
        v.w = fmaxf(v.w * sscale[c + 3] + sshift[c + 3], 0.f);
        *(float4*)(io + (size_t)i4 * 4) = v;
    }
}

extern "C" void kernel_launch(void* const* d_in, const int* in_sizes, int n_in,
                              void* d_out, int out_size, void* d_ws, size_t ws_size,
                              hipStream_t stream) {
    const float* x   = (const float*)d_in[0];
    const int*   ei  = (const int*)d_in[1];
    const float* c1w = (const float*)d_in[2];
    const float* c1b = (const float*)d_in[3];
    const float* gw  = (const float*)d_in[4];
    const float* gb  = (const float*)d_in[5];
    const float* c2w = (const float*)d_in[6];
    const float* c2b = (const float*)d_in[7];
    const float* bng = (const float*)d_in[8];
    const float* bnb = (const float*)d_in[9];
    float* out = (float*)d_out;

    // workspace layout (floats)
    float* h2      = (float*)d_ws;               // ROWS*64 = 8,192,000
    float* Wc1     = h2 + (size_t)ROWS * 64;     // 12288
    float* Wc2     = Wc1 + 12288;                // 12288
    float* b1c     = Wc2 + 12288;                // 64
    float* dinv    = b1c + 64;                   // 2000
    float* snorm   = dinv + 2000;                // 32000
    float* bnstats = snorm + 32000;              // 128
    int*   degi    = (int*)(bnstats + 128);      // 2000
    int*   offs    = degi + 2000;                // 2001
    int*   cursor  = offs + 2001;                // 2000
    int*   ssrc    = cursor + 2000;              // 32000

    float* xh = out;   // stage-1 output parked in d_out (dead before conv2 overwrites)

    hipMemsetAsync(degi, 0, sizeof(int) * 2000, stream);
    hipMemsetAsync(cursor, 0, sizeof(int) * 2000, stream);
    hipMemsetAsync(bnstats, 0, sizeof(float) * 128, stream);

    k_deg<<<(E_DIM + 255) / 256, 256, 0, stream>>>(ei, degi);
    k_dinv<<<(N_DIM + 255) / 256, 256, 0, stream>>>(degi, dinv);
    k_scan<<<1, 1024, 0, stream>>>(degi, offs);
    k_fill<<<(E_DIM + 255) / 256, 256, 0, stream>>>(ei, offs, dinv, cursor, ssrc, snorm);
    k_wprep<<<48, 256, 0, stream>>>(c1w, c1b, gw, c2w, Wc1, Wc2, b1c);

    // stage 1: fused conv1 + GCN linear -> xh (in d_out)
    k_gemm<<<ROWS / 64, 256, 0, stream>>>(x, Wc1, b1c, xh, nullptr, 0);
    // stage 2: GCN aggregation -> h2 (ws)
    k_gather<<<ROWS / 4, 256, 0, stream>>>(xh, offs, ssrc, snorm, dinv, gb, h2);
    // stage 3: conv2 -> out (pre-BN) + BN stats
    k_gemm<<<ROWS / 64, 256, 0, stream>>>(h2, Wc2, c2b, out, bnstats, 1);
    // stage 4: BN + ReLU in place
    k_bn<<<2048, 256, 0, stream>>>(out, bnstats, bng, bnb);
}

// Round 3
// 270.834 us; speedup vs baseline: 1.8957x; 1.8957x over previous
//
#include <hip/hip_runtime.h>

#define T_DIM 64
#define N_DIM 2000
#define C_DIM 64
#define E_DIM 32000
#define ROWS (T_DIM * N_DIM)   // 128000
#define BN_EPS 1e-5f

typedef short s8v __attribute__((ext_vector_type(8)));
typedef float f4v __attribute__((ext_vector_type(4)));

__device__ __forceinline__ ushort f2b(float f) {
    unsigned u = __float_as_uint(f);
    unsigned r = u + 0x7FFF + ((u >> 16) & 1);
    return (ushort)(r >> 16);
}
__device__ __forceinline__ float b2f(ushort h) {
    return __uint_as_float(((unsigned)h) << 16);
}

// ---------------- prep kernels ----------------

__global__ void k_deg(const int* __restrict__ ei, int* __restrict__ deg) {
    int e = blockIdx.x * 256 + threadIdx.x;
    if (e < E_DIM) atomicAdd(&deg[ei[E_DIM + e]], 1);
}

__global__ void k_dinv(const int* __restrict__ deg, float* __restrict__ dinv) {
    int n = blockIdx.x * 256 + threadIdx.x;
    if (n < N_DIM) dinv[n] = rsqrtf((float)(deg[n] + 1));  // +1 self-loop
}

// exclusive prefix sum of (deg[n]+1) -> offs[0..N_DIM]  (self-loop slot included)
__global__ void k_scan(const int* __restrict__ deg, int* __restrict__ offs) {
    __shared__ int a[2048], b[2048];
    int tid = threadIdx.x;
    for (int i = tid; i < 2048; i += 1024) a[i] = (i < N_DIM) ? (deg[i] + 1) : 0;
    __syncthreads();
    int* s = a; int* d = b;
    for (int off = 1; off < 2048; off <<= 1) {
        for (int i = tid; i < 2048; i += 1024)
            d[i] = s[i] + ((i >= off) ? s[i - off] : 0);
        __syncthreads();
        int* t = s; s = d; d = t;
    }
    for (int i = tid; i < 2048; i += 1024)
        if (i <= N_DIM) offs[i] = (i == 0) ? 0 : s[i - 1];
}

// self-edge in slot 0 of each node's CSR range; cursor starts at 1
__global__ void k_self(const int* __restrict__ offs, const float* __restrict__ dinv,
                       int* __restrict__ cursor, int2* __restrict__ edat) {
    int n = blockIdx.x * 256 + threadIdx.x;
    if (n < N_DIM) {
        float dn = dinv[n];
        edat[offs[n]] = make_int2(n, __float_as_int(dn * dn));
        cursor[n] = 1;
    }
}

__global__ void k_fill(const int* __restrict__ ei, const int* __restrict__ offs,
                       const float* __restrict__ dinv, int* __restrict__ cursor,
                       int2* __restrict__ edat) {
    int e = blockIdx.x * 256 + threadIdx.x;
    if (e < E_DIM) {
        int s = ei[e];
        int d = ei[E_DIM + e];
        int p = atomicAdd(&cursor[d], 1);
        edat[offs[d] + p] = make_int2(s, __float_as_int(dinv[s] * dinv[d]));
    }
}

// Weights -> bf16, pre-swizzled into MFMA B-fragment order.
// kk in [0,192): k3=kk/64, i=kk%64.  frag flat idx for (kk,n):
//   s=kk>>5, q=(kk>>3)&3, j=kk&7, cc=n>>4, m=n&15
//   flat = (((s*4+cc)*64) + q*16 + m)*8 + j     (max 12287)
__global__ void k_wprep(const float* __restrict__ c1w, const float* __restrict__ c1b,
                        const float* __restrict__ gw, const float* __restrict__ c2w,
                        ushort* __restrict__ W1f, ushort* __restrict__ W2f,
                        float* __restrict__ b1c) {
    int gid = blockIdx.x * 256 + threadIdx.x;   // 48*256 = 12288
    if (gid < 192 * 64) {
        int kk = gid >> 6, n = gid & 63;
        int k3 = kk >> 6;  // kk/64
        int i = kk & 63;
        float s1 = 0.f;
        for (int o = 0; o < 64; ++o)
            s1 += c1w[o * 192 + i * 3 + k3] * gw[o * 64 + n];
        float s2 = c2w[n * 192 + i * 3 + k3];
        int s = kk >> 5, q = (kk >> 3) & 3, j = kk & 7, cc = n >> 4, m = n & 15;
        int flat = (((s * 4 + cc) * 64) + q * 16 + m) * 8 + j;
        W1f[flat] = f2b(s1);
        W2f[flat] = f2b(s2);
        if (gid < 64) {
            float bs = 0.f;
            for (int o = 0; o < 64; ++o) bs += c1b[o] * gw[o * 64 + gid];
            b1c[gid] = bs;
        }
    }
}

// ---------------- MFMA conv-GEMM ----------------
// out[r][n] = bias[n] + sum_{k3,i} A[r+(k3-1)*N][i] * W[k3][i][n]
// tile: 64 rows/block, 4 waves; wave w computes rows [w*16, w*16+16) x 64 cols.
// AFP32: A is fp32 (conv1, x) -> out bf16 (xh). else A bf16 (h2) -> out fp32 + BN stats.
template<int AFP32>
__global__ __launch_bounds__(256) void k_conv(
    const void* __restrict__ Ap, const ushort* __restrict__ Wf,
    const float* __restrict__ bias, void* __restrict__ outp,
    float* __restrict__ bnstats) {
    // Asl: 3 slabs, each 64 rows x 64 ch in A-fragment order (4096 shorts = 8KB)
    __shared__ __align__(16) ushort AslU[3 * 4096];    // 24 KB (reused as epilogue buf)
    __shared__ __align__(16) ushort Wl[12288];         // 24 KB
    __shared__ float ssum[64], ssq[64];

    int tid = threadIdx.x;
    int wv = tid >> 6, lane = tid & 63;
    int row0 = blockIdx.x * 64;

    if (!AFP32 && tid < 64) { ssum[tid] = 0.f; ssq[tid] = 0.f; }

    // stage W (already frag-ordered): 12288 ushorts = 1536 x 16B octets
    // (round-2 bug: this loop ran o<3 and copied only half of W)
    #pragma unroll
    for (int o = 0; o < 6; ++o) {
        int idx = tid + o * 256;
        *(s8v*)&Wl[idx * 8] = *(const s8v*)&Wf[idx * 8];
    }

    // stage 3 A slabs into fragment order
    #pragma unroll
    for (int k3 = 0; k3 < 3; ++k3) {
        int shift = (k3 - 1) * N_DIM;
        #pragma unroll
        for (int o = 0; o < 2; ++o) {
            int p = tid + o * 256;           // octet id 0..511
            int r = p >> 3, c = (p & 7) * 8; // row in tile, channel base
            int gr = row0 + r;
            int t = gr / N_DIM;
            int ts = t + k3 - 1;
            int s2 = c >> 5, q = (c >> 3) & 3, m = r & 15, wr = r >> 4;
            ushort* dst = &AslU[k3 * 4096 + (((s2 * 4 + wr) * 64) + q * 16 + m) * 8];
            if (AFP32) {
                s8v pk = {0, 0, 0, 0, 0, 0, 0, 0};
                if (ts >= 0 && ts < T_DIM) {
                    const float* src = (const float*)Ap + (size_t)(gr + shift) * 64 + c;
                    float4 v0 = *(const float4*)src;
                    float4 v1 = *(const float4*)(src + 4);
                    pk[0] = (short)f2b(v0.x); pk[1] = (short)f2b(v0.y);
                    pk[2] = (short)f2b(v0.z); pk[3] = (short)f2b(v0.w);
                    pk[4] = (short)f2b(v1.x); pk[5] = (short)f2b(v1.y);
                    pk[6] = (short)f2b(v1.z); pk[7] = (short)f2b(v1.w);
                }
                *(s8v*)dst = pk;
            } else {
                s8v pk = {0, 0, 0, 0, 0, 0, 0, 0};
                if (ts >= 0 && ts < T_DIM)
                    pk = *(const s8v*)((const ushort*)Ap + (size_t)(gr + shift) * 64 + c);
                *(s8v*)dst = pk;
            }
        }
    }
    __syncthreads();

    f4v acc[4];
    #pragma unroll
    for (int c = 0; c < 4; ++c) acc[c] = (f4v){0.f, 0.f, 0.f, 0.f};

    #pragma unroll
    for (int sg = 0; sg < 6; ++sg) {
        s8v af = *(const s8v*)&AslU[(sg >> 1) * 4096 + ((((sg & 1) * 4 + wv) * 64) + lane) * 8];
        #pragma unroll
        for (int c = 0; c < 4; ++c) {
            s8v bf = *(const s8v*)&Wl[((sg * 4 + c) * 64 + lane) * 8];
            acc[c] = __builtin_amdgcn_mfma_f32_16x16x32_bf16(af, bf, acc[c], 0, 0, 0);
        }
    }

    __syncthreads();   // Asl dead; reuse as epilogue buffer

    int m = lane & 15, q = lane >> 4;
    if (AFP32) {
        // write bf16 xh via LDS transpose (row stride 80 shorts, 16B aligned)
        ushort* eb = AslU;
        #pragma unroll
        for (int c = 0; c < 4; ++c) {
            int col = c * 16 + m;
            float bb = bias[col];
            #pragma unroll
            for (int rg = 0; rg < 4; ++rg) {
                int lrow = wv * 16 + q * 4 + rg;
                eb[lrow * 80 + col] = f2b(acc[c][rg] + bb);
            }
        }
        __syncthreads();
        ushort* out = (ushort*)outp;
        #pragma unroll
        for (int o = 0; o < 2; ++o) {
            int p = tid + o * 256;
            int r = p >> 3, c = (p & 7) * 8;
            *(s8v*)&out[(size_t)(row0 + r) * 64 + c] = *(const s8v*)&eb[r * 80 + c];
        }
    } else {
        float* ef = (float*)AslU;   // row stride 68 floats (272B, 16B aligned)
        float bsum[4] = {0.f, 0.f, 0.f, 0.f};
        float bsq[4] = {0.f, 0.f, 0.f, 0.f};
        #pragma unroll
        for (int c = 0; c < 4; ++c) {
            int col = c * 16 + m;
            float bb = bias[col];
            #pragma unroll
            for (int rg = 0; rg < 4; ++rg) {
                int lrow = wv * 16 + q * 4 + rg;
                float v = acc[c][rg] + bb;
                ef[lrow * 68 + col] = v;
                bsum[c] += v;
                bsq[c] += v * v;
            }
        }
        #pragma unroll
        for (int c = 0; c < 4; ++c) {
            atomicAdd(&ssum[c * 16 + m], bsum[c]);
            atomicAdd(&ssq[c * 16 + m], bsq[c]);
        }
        __syncthreads();
        float* out = (float*)outp;
        #pragma unroll
        for (int o = 0; o < 4; ++o) {
            int p = tid + o * 256;          // float4 chunk id 0..1023
            int r = p >> 4, c4 = (p & 15) * 4;
            *(float4*)&out[(size_t)(row0 + r) * 64 + c4] = *(const float4*)&ef[r * 68 + c4];
        }
        if (tid < 64) {
            atomicAdd(&bnstats[tid], ssum[tid]);
            atomicAdd(&bnstats[64 + tid], ssq[tid]);
        }
    }
}

// ---------------- GCN aggregation: 8 parallel edge-slots per wave ----------------
__global__ __launch_bounds__(256) void k_gather(
    const ushort* __restrict__ xhb, const int* __restrict__ offs,
    const int2* __restrict__ edat, const float* __restrict__ gcn_b,
    ushort* __restrict__ h2b) {
    int unit = blockIdx.x * 4 + (threadIdx.x >> 6);   // one wave per (t,n)
    int lane = threadIdx.x & 63;
    int g = lane >> 3;            // edge slot 0..7
    int c8 = (lane & 7) * 8;      // channel base
    int t = unit / N_DIM;
    int n = unit - t * N_DIM;
    int beg = offs[n], end = offs[n + 1];
    const ushort* base = xhb + (size_t)t * N_DIM * 64 + c8;

    float a[8] = {0.f, 0.f, 0.f, 0.f, 0.f, 0.f, 0.f, 0.f};
    for (int j = beg + g; j < end; j += 8) {
        int2 e = edat[j];
        float w = __int_as_float(e.y);
        s8v v = *(const s8v*)(base + (size_t)e.x * 64);
        #pragma unroll
        for (int i = 0; i < 8; ++i) a[i] += w * b2f((ushort)v[i]);
    }
    #pragma unroll
    for (int d = 8; d <= 32; d <<= 1)
        #pragma unroll
        for (int i = 0; i < 8; ++i) a[i] += __shfl_xor(a[i], d);

    if (g == 0) {
        s8v pk;
        #pragma unroll
        for (int i = 0; i < 8; ++i) pk[i] = (short)f2b(a[i] + gcn_b[c8 + i]);
        *(s8v*)&h2b[(size_t)unit * 64 + c8] = pk;
    }
}

// ---------------- BN (train-mode stats) + ReLU, in place ----------------
__global__ __launch_bounds__(256) void k_bn(float* __restrict__ io,
                                            const float* __restrict__ bnstats,
                                            const float* __restrict__ gamma,
                                            const float* __restrict__ beta) {
    __shared__ float sscale[64], sshift[64];
    int tid = threadIdx.x;
    if (tid < 64) {
        float m = bnstats[tid] * (1.0f / ROWS);
        float v = bnstats[64 + tid] * (1.0f / ROWS) - m * m;
        float sc = gamma[tid] * rsqrtf(v + BN_EPS);
        sscale[tid] = sc;
        sshift[tid] = beta[tid] - m * sc;
    }
    __syncthreads();
    const int total4 = ROWS * 64 / 4;
    for (int i4 = blockIdx.x * 256 + tid; i4 < total4; i4 += gridDim.x * 256) {
        float4 v = *(const float4*)(io + (size_t)i4 * 4);
        int c = (i4 * 4) & 63;
        v.x = fmaxf(v.x * sscale[c + 0] + sshift[c + 0], 0.f);
        v.y = fmaxf(v.y * sscale[c + 1] + sshift[c + 1], 0.f);
        v.z = fmaxf(v.z * sscale[c + 2] + sshift[c + 2], 0.f);
        v.w = fmaxf(v.w * sscale[c + 3] + sshift[c + 3], 0.f);
        *(float4*)(io + (size_t)i4 * 4) = v;
    }
}

extern "C" void kernel_launch(void* const* d_in, const int* in_sizes, int n_in,
                              void* d_out, int out_size, void* d_ws, size_t ws_size,
                              hipStream_t stream) {
    const float* x   = (const float*)d_in[0];
    const int*   ei  = (const int*)d_in[1];
    const float* c1w = (const float*)d_in[2];
    const float* c1b = (const float*)d_in[3];
    const float* gw  = (const float*)d_in[4];
    const float* gb  = (const float*)d_in[5];
    const float* c2w = (const float*)d_in[6];
    const float* c2b = (const float*)d_in[7];
    const float* bng = (const float*)d_in[8];
    const float* bnb = (const float*)d_in[9];
    float* out = (float*)d_out;

    // workspace layout
    ushort* h2b    = (ushort*)d_ws;                       // ROWS*64 bf16 = 16.4 MB
    ushort* W1f    = h2b + (size_t)ROWS * 64;             // 12288
    ushort* W2f    = W1f + 12288;                         // 12288
    float*  b1c    = (float*)(W2f + 12288);               // 64
    float*  dinv   = b1c + 64;                            // 2000
    float*  bnstats= dinv + 2000;                         // 128
    int*    degi   = (int*)(bnstats + 128);               // 2000
    int*    offs   = degi + 2000;                         // 2001
    int*    cursor = offs + 2001;                         // 2000
    int2*   edat   = (int2*)((char*)(cursor + 2000) +
                     (((size_t)(cursor + 2000)) % 8 ? 4 : 0)); // E+N int2

    ushort* xhb = (ushort*)d_out;   // bf16 xh parked in d_out (dead before conv2 writes)

    hipMemsetAsync(degi, 0, sizeof(int) * N_DIM, stream);
    hipMemsetAsync(bnstats, 0, sizeof(float) * 128, stream);

    k_deg<<<(E_DIM + 255) / 256, 256, 0, stream>>>(ei, degi);
    k_dinv<<<(N_DIM + 255) / 256, 256, 0, stream>>>(degi, dinv);
    k_scan<<<1, 1024, 0, stream>>>(degi, offs);
    k_self<<<(N_DIM + 255) / 256, 256, 0, stream>>>(offs, dinv, cursor, edat);
    k_fill<<<(E_DIM + 255) / 256, 256, 0, stream>>>(ei, offs, dinv, cursor, edat);
    k_wprep<<<48, 256, 0, stream>>>(c1w, c1b, gw, c2w, W1f, W2f, b1c);

    // stage 1: fused conv1 + GCN linear -> xh bf16 (in d_out)
    k_conv<1><<<ROWS / 64, 256, 0, stream>>>(x, W1f, b1c, xhb, nullptr);
    // stage 2: GCN aggregation -> h2 bf16 (ws)
    k_gather<<<ROWS / 4, 256, 0, stream>>>(xhb, offs, edat, gb, h2b);
    // stage 3: conv2 -> out fp32 (d_out) + BN stats
    k_conv<0><<<ROWS / 64, 256, 0, stream>>>(h2b, W2f, c2b, out, bnstats);
    // stage 4: BN + ReLU in place
    k_bn<<<2048, 256, 0, stream>>>(out, bnstats, bng, bnb);
}